// Round 15
// baseline (142.518 us; speedup 1.0000x reference)
//
#include <hip/hip_runtime.h>

#define B_TOTAL 32768
#define NROWB   128            // rows per block
#define TILE    32             // rows per tile
#define NT      4              // tiles per block

typedef __attribute__((ext_vector_type(8)))  short    bf16x8;
typedef __attribute__((ext_vector_type(4)))  float    f32x4;
typedef __attribute__((ext_vector_type(4)))  unsigned u32x4;

__device__ __forceinline__ unsigned rne1(float f) {
    unsigned u = __builtin_bit_cast(unsigned, f);
    return (u + 0x7FFFu + ((u >> 16) & 1u)) >> 16;
}
__device__ __forceinline__ unsigned cvtpk(float lo, float hi) {
    unsigned r;
    asm("v_cvt_pk_bf16_f32 %0, %1, %2" : "=v"(r) : "v"(lo), "v"(hi));
    return r;
}
__device__ __forceinline__ float fsig(float v) {
    return __fdividef(1.0f, 1.0f + __expf(-v));
}
__device__ __forceinline__ float ftanh(float v) {
    return 1.0f - __fdividef(2.0f, 1.0f + __expf(2.0f * v));
}
// DCE guards (rule #17)
__device__ __forceinline__ void sinkf(float v) { asm volatile("" :: "v"(v)); }
__device__ __forceinline__ void sinkb(const bf16x8& w) {
    union { bf16x8 v; unsigned u[4]; } q; q.v = w;
    asm volatile("" :: "v"(q.u[0]), "v"(q.u[1]), "v"(q.u[2]), "v"(q.u[3]));
}

// Weights -> fragment-linear bf16 for mfma 16x16x32 (R5 layout, cs = 0..7).
__global__ void wconv_kernel(const float* __restrict__ w1, const float* __restrict__ w2,
                             const float* __restrict__ wf, const float* __restrict__ w3,
                             u32x4* __restrict__ out) {
    int T = blockIdx.x * 256 + threadIdx.x;
    int F = T >> 6, l = T & 63;
    int cs = F >> 5, g = (F >> 3) & 3, ks = F & 7;
    const float* W = (g == 0) ? w1 : (g == 1) ? w2 : (g == 2) ? wf : w3;
    const float* s = W + (cs * 16 + (l & 15)) * 256 + ks * 32 + (l >> 4) * 8;
    f32x4 lo = *(const f32x4*)s;
    f32x4 hi = *(const f32x4*)(s + 4);
    u32x4 r;
    r[0] = rne1(lo[0]) | (rne1(lo[1]) << 16);
    r[1] = rne1(lo[2]) | (rne1(lo[3]) << 16);
    r[2] = rne1(hi[0]) | (rne1(hi[1]) << 16);
    r[3] = rne1(hi[2]) | (rne1(hi[3]) << 16);
    out[T] = r;
}

// ABLATION at the R14 structure (256 blocks x 512 thr, counted vmcnt):
// V0 = memory-only, V1 = compute-only, V2 = full (exact R14, correct output).
// V0/V1 run REPS=4 so their dispatches outlast the 40-us fill dispatches
// and surface in the top-5 table; read dur/4 per pass.
template<int V, int REPS>
__global__ __launch_bounds__(512, 2) void lstm_kernel(
    const float* __restrict__ x, const float* __restrict__ h, const float* __restrict__ c,
    const bf16x8* __restrict__ wfrag,
    const float* __restrict__ b1, const float* __restrict__ b2,
    const float* __restrict__ bfv, const float* __restrict__ b3,
    float* __restrict__ out)
{
    __shared__ __align__(16) char smem[2][TILE * 1024];   // 64 KB

    const int tid  = threadIdx.x;
    const int wave = tid >> 6;
    const int lane = tid & 63;
    const int rb   = lane & 15;
    const int c4   = lane >> 4;
    const long row0 = (long)blockIdx.x * NROWB;
    const int gcol4 = wave * 16 + c4 * 4;

    auto STAGE = [&](int b, int tc) {
        char* buf = smem[b & 1];
        const long gr0 = row0 + (long)tc * TILE;
#pragma unroll
        for (int i = 0; i < 4; ++i) {
            const int r = wave * 4 + i;
            const unsigned kb = ((unsigned)lane * 16u) ^ (((unsigned)r & 7u) << 4);
            const float* src = (kb < 512u)
                ? (x + (gr0 + r) * 128 + (kb >> 2))
                : (h + (gr0 + r) * 128 + ((kb - 512u) >> 2));
            __builtin_amdgcn_global_load_lds(
                (const __attribute__((address_space(1))) unsigned*)src,
                (__attribute__((address_space(3))) unsigned*)(buf + r * 1024),
                16, 0, 0);
        }
    };

    if constexpr (V != 1) STAGE(0, 0);

    bf16x8 wfr[4][8];
#pragma unroll
    for (int g = 0; g < 4; ++g)
#pragma unroll
        for (int ks = 0; ks < 8; ++ks)
            wfr[g][ks] = wfrag[(size_t)(wave * 32 + g * 8 + ks) * 64 + lane];

    f32x4 bias[4];
    bias[0] = *(const f32x4*)(b1 + gcol4);
    bias[1] = *(const f32x4*)(b2 + gcol4);
    bias[2] = *(const f32x4*)(bfv + gcol4);
    bias[3] = *(const f32x4*)(b3 + gcol4);

    f32x4 cv0, cv1;
    if constexpr (V != 1) {
        cv0 = *(const f32x4*)(c + (row0 + rb) * 128 + gcol4);
        cv1 = *(const f32x4*)(c + (row0 + 16 + rb) * 128 + gcol4);
    } else {
        cv0 = bias[0]; cv1 = bias[1];
    }

    float* out_h = out;
    float* out_c = out + (size_t)B_TOTAL * 128;

#pragma unroll 1
    for (int rep = 0; rep < REPS; ++rep) {
#pragma unroll 1
        for (int t = 0; t < NT; ++t) {
            if constexpr (V != 1) {
                asm volatile("s_waitcnt vmcnt(6)" ::: "memory");
            }
            __builtin_amdgcn_s_barrier();
            __builtin_amdgcn_sched_barrier(0);

            const int tn = (t + 1 < NT) ? (t + 1) : (NT - 1);
            f32x4 ncv0, ncv1;
            if constexpr (V != 1) {
                STAGE(t + 1, tn);
                ncv0 = *(const f32x4*)(c + (row0 + (long)tn * TILE + rb) * 128 + gcol4);
                ncv1 = *(const f32x4*)(c + (row0 + (long)tn * TILE + 16 + rb) * 128 + gcol4);
            }

            const char* buf = smem[t & 1];
            const long gr0 = row0 + (long)t * TILE;

            f32x4 acc[2][4];
#pragma unroll
            for (int g = 0; g < 4; ++g) { acc[0][g] = bias[g]; acc[1][g] = bias[g]; }

            if constexpr (V != 0) {
#pragma unroll
                for (int ks = 0; ks < 8; ++ks) {
                    bf16x8 af[2];
#pragma unroll
                    for (int mt = 0; mt < 2; ++mt) {
                        const int r = mt * 16 + rb;
                        const unsigned swz = ((unsigned)r & 7u) << 4;
                        const unsigned kb  = (unsigned)(ks * 128 + c4 * 32);
                        const char* p = buf + r * 1024;
                        f32x4 a0 = *(const f32x4*)(p + (kb ^ swz));
                        f32x4 a1 = *(const f32x4*)(p + ((kb + 16u) ^ swz));
                        union { unsigned u[4]; bf16x8 v; } pk;
                        pk.u[0] = cvtpk(a0[0], a0[1]);
                        pk.u[1] = cvtpk(a0[2], a0[3]);
                        pk.u[2] = cvtpk(a1[0], a1[1]);
                        pk.u[3] = cvtpk(a1[2], a1[3]);
                        af[mt] = pk.v;
                    }
#pragma unroll
                    for (int g = 0; g < 4; ++g) {
                        acc[0][g] = __builtin_amdgcn_mfma_f32_16x16x32_bf16(wfr[g][ks], af[0], acc[0][g], 0, 0, 0);
                        acc[1][g] = __builtin_amdgcn_mfma_f32_16x16x32_bf16(wfr[g][ks], af[1], acc[1][g], 0, 0, 0);
                    }
                }
            }

#pragma unroll
            for (int mt = 0; mt < 2; ++mt) {
                const f32x4 cv = mt ? cv1 : cv0;
                const long o = (gr0 + mt * 16 + rb) * 128 + gcol4;
                if constexpr (V == 0) {
                    *(f32x4*)(out_h + o) = cv;
                    *(f32x4*)(out_c + o) = cv;
                } else {
                    f32x4 nh, nc;
#pragma unroll
                    for (int j = 0; j < 4; ++j) {
                        const float g1 = fsig(acc[mt][0][j]);
                        const float g2 = fsig(acc[mt][1][j]);
                        const float gf = ftanh(acc[mt][2][j]);
                        const float g3 = fsig(acc[mt][3][j]);
                        nc[j] = cv[j] * g1 + g2 * gf;
                        nh[j] = ftanh(nc[j]) * g3;
                    }
                    if constexpr (V == 1) {
#pragma unroll
                        for (int j = 0; j < 4; ++j) { sinkf(nh[j]); sinkf(nc[j]); }
                    } else {
                        *(f32x4*)(out_h + o) = nh;
                        *(f32x4*)(out_c + o) = nc;
                    }
                }
            }

            if constexpr (V != 1) { cv0 = ncv0; cv1 = ncv1; }
        }
        if constexpr (V == 0) {   // pin resident weights live across reps
#pragma unroll
            for (int g = 0; g < 4; ++g)
#pragma unroll
                for (int ks = 0; ks < 8; ++ks) sinkb(wfr[g][ks]);
        }
    }
}

extern "C" void kernel_launch(void* const* d_in, const int* in_sizes, int n_in,
                              void* d_out, int out_size, void* d_ws, size_t ws_size,
                              hipStream_t stream) {
    (void)in_sizes; (void)n_in; (void)out_size; (void)ws_size;
    const float* x  = (const float*)d_in[0];
    const float* h  = (const float*)d_in[1];
    const float* c  = (const float*)d_in[2];
    const float* W1 = (const float*)d_in[3];
    const float* b1 = (const float*)d_in[4];
    const float* W2 = (const float*)d_in[5];
    const float* b2 = (const float*)d_in[6];
    const float* Wf = (const float*)d_in[7];
    const float* bf = (const float*)d_in[8];
    const float* W3 = (const float*)d_in[9];
    const float* b3 = (const float*)d_in[10];

    wconv_kernel<<<64, 256, 0, stream>>>(W1, W2, Wf, W3, (u32x4*)d_ws);
    const int grid = B_TOTAL / NROWB;   // 256 blocks
    // V0 (memory-only, x4) and V1 (compute-only, x4) are diagnostics;
    // V2 runs last and produces the final correct output.
    lstm_kernel<0, 4><<<grid, 512, 0, stream>>>(x, h, c, (const bf16x8*)d_ws, b1, b2, bf, b3, (float*)d_out);
    lstm_kernel<1, 4><<<grid, 512, 0, stream>>>(x, h, c, (const bf16x8*)d_ws, b1, b2, bf, b3, (float*)d_out);
    lstm_kernel<2, 1><<<grid, 512, 0, stream>>>(x, h, c, (const bf16x8*)d_ws, b1, b2, bf, b3, (float*)d_out);
}

// Round 16
// 32.281 us; speedup vs baseline: 4.4149x; 4.4149x over previous
//
#include <hip/hip_runtime.h>

#define B_TOTAL 32768
#define NROWB   128            // rows per block
#define TILE    32             // rows per tile
#define NT      4              // tiles per block

typedef __attribute__((ext_vector_type(8)))  short    bf16x8;
typedef __attribute__((ext_vector_type(4)))  float    f32x4;
typedef __attribute__((ext_vector_type(4)))  unsigned u32x4;

// round-to-nearest-even fp32 -> bf16 (weights, one-time)
__device__ __forceinline__ unsigned rne1(float f) {
    unsigned u = __builtin_bit_cast(unsigned, f);
    return (u + 0x7FFFu + ((u >> 16) & 1u)) >> 16;
}
// HW packed fp32x2 -> bf16x2 (gfx950; no builtin)
__device__ __forceinline__ unsigned cvtpk(float lo, float hi) {
    unsigned r;
    asm("v_cvt_pk_bf16_f32 %0, %1, %2" : "=v"(r) : "v"(lo), "v"(hi));
    return r;
}
__device__ __forceinline__ float fsig(float v) {
    return __fdividef(1.0f, 1.0f + __expf(-v));
}
__device__ __forceinline__ float ftanh(float v) {
    return 1.0f - __fdividef(2.0f, 1.0f + __expf(2.0f * v));
}

// Weights -> fragment-linear bf16 for mfma 16x16x32 (R5 layout, cs = 0..7).
// Frag F = cs*32 + g*8 + ks; lane l: W_g[n = cs*16 + (l&15)][k = ks*32 + (l>>4)*8 + e]
__global__ void wconv_kernel(const float* __restrict__ w1, const float* __restrict__ w2,
                             const float* __restrict__ wf, const float* __restrict__ w3,
                             u32x4* __restrict__ out) {
    int T = blockIdx.x * 256 + threadIdx.x;
    int F = T >> 6, l = T & 63;
    int cs = F >> 5, g = (F >> 3) & 3, ks = F & 7;
    const float* W = (g == 0) ? w1 : (g == 1) ? w2 : (g == 2) ? wf : w3;
    const float* s = W + (cs * 16 + (l & 15)) * 256 + ks * 32 + (l >> 4) * 8;
    f32x4 lo = *(const f32x4*)s;
    f32x4 hi = *(const f32x4*)(s + 4);
    u32x4 r;
    r[0] = rne1(lo[0]) | (rne1(lo[1]) << 16);
    r[1] = rne1(lo[2]) | (rne1(lo[3]) << 16);
    r[2] = rne1(hi[0]) | (rne1(hi[1]) << 16);
    r[3] = rne1(hi[2]) | (rne1(hi[3]) << 16);
    out[T] = r;
}

// R16: bf16 LDS staging -- convert ONCE per element (reg-staged), read ONCE.
// 256 blocks x 512 thr (8 waves = all 128 cols), 128 rows as 4 tiles of 32.
// bf16 A-tile layout [8 ks][32 rows][64 B]: the wave's af read is one
// ds_read_b128 over a CONTIGUOUS 1 KB block -> zero bank conflicts, and
// addressing folds into immediate offsets. Hot loop per wave-tile:
// 16 ds_read + 64 MFMA, ZERO cvtpk (was 32 reads + 64 cvtpk).
// Sync: raw s_barrier + lgkmcnt(0) only; A-loads are registers (compiler-
// tracked waits), issued one full body ahead -> HBM latency hidden.
__global__ __launch_bounds__(512, 2) void lstm_kernel(
    const float* __restrict__ x, const float* __restrict__ h, const float* __restrict__ c,
    const bf16x8* __restrict__ wfrag,
    const float* __restrict__ b1, const float* __restrict__ b2,
    const float* __restrict__ bfv, const float* __restrict__ b3,
    float* __restrict__ out)
{
    __shared__ __align__(16) char smem[2][16384];   // 32 KB bf16 A dbuf

    const int tid  = threadIdx.x;
    const int wave = tid >> 6;                // col-slice cs = wave (0..7)
    const int lane = tid & 63;
    const int rb   = lane & 15;               // batch row within 16
    const int c4   = lane >> 4;               // 0..3
    const long row0 = (long)blockIdx.x * NROWB;
    const int gcol4 = wave * 16 + c4 * 4;     // 4 consecutive gate cols

    const int srow   = wave * 4 + (lane >> 4);   // staging row 0..31
    const int kchunk = lane & 15;                // 16 fp32 per chunk

    // A-staging registers: one tile in flight (16 fp32/lane)
    f32x4 ar[4];
    auto A_ISSUE = [&](int t) {                  // issue global loads, tile t
        const float* base = (kchunk < 8)
            ? (x + (row0 + (long)t * TILE + srow) * 128 + kchunk * 16)
            : (h + (row0 + (long)t * TILE + srow) * 128 + (kchunk - 8) * 16);
        ar[0] = *(const f32x4*)(base);
        ar[1] = *(const f32x4*)(base + 4);
        ar[2] = *(const f32x4*)(base + 8);
        ar[3] = *(const f32x4*)(base + 12);
    };
    auto A_STORE = [&](int b) {                  // cvtpk + ds_write to buf b&1
        u32x4 w0, w1;
        w0[0] = cvtpk(ar[0][0], ar[0][1]);
        w0[1] = cvtpk(ar[0][2], ar[0][3]);
        w0[2] = cvtpk(ar[1][0], ar[1][1]);
        w0[3] = cvtpk(ar[1][2], ar[1][3]);
        w1[0] = cvtpk(ar[2][0], ar[2][1]);
        w1[1] = cvtpk(ar[2][2], ar[2][3]);
        w1[2] = cvtpk(ar[3][0], ar[3][1]);
        w1[3] = cvtpk(ar[3][2], ar[3][3]);
        // dest: ks = kchunk>>1, 32B half = kchunk&1  ([ks][row][64B] layout)
        char* dst = smem[b & 1] + (kchunk >> 1) * 2048 + srow * 64 + (kchunk & 1) * 32;
        *(u32x4*)(dst)      = w0;
        *(u32x4*)(dst + 16) = w1;
    };

    // ---- prologue ----
    A_ISSUE(0);

    bf16x8 wfr[4][8];                            // resident weights, 128 VGPR
#pragma unroll
    for (int g = 0; g < 4; ++g)
#pragma unroll
        for (int ks = 0; ks < 8; ++ks)
            wfr[g][ks] = wfrag[(size_t)(wave * 32 + g * 8 + ks) * 64 + lane];

    f32x4 bias[4];
    bias[0] = *(const f32x4*)(b1 + gcol4);
    bias[1] = *(const f32x4*)(b2 + gcol4);
    bias[2] = *(const f32x4*)(bfv + gcol4);
    bias[3] = *(const f32x4*)(b3 + gcol4);

    A_STORE(0);                                  // tile 0 -> buf 0
    A_ISSUE(1);                                  // tile 1 in flight

    f32x4 cv0 = *(const f32x4*)(c + (row0 + rb) * 128 + gcol4);
    f32x4 cv1 = *(const f32x4*)(c + (row0 + 16 + rb) * 128 + gcol4);

    float* out_h = out;
    float* out_c = out + (size_t)B_TOTAL * 128;

#pragma unroll 1
    for (int t = 0; t < NT; ++t) {
        asm volatile("s_waitcnt lgkmcnt(0)" ::: "memory");   // my ds_writes done
        __builtin_amdgcn_s_barrier();            // buf[t&1] complete everywhere
        __builtin_amdgcn_sched_barrier(0);

        const char* buf = smem[t & 1];
        const long gr0 = row0 + (long)t * TILE;

        f32x4 acc[2][4];                         // [m-tile][gate], bias-init
#pragma unroll
        for (int g = 0; g < 4; ++g) { acc[0][g] = bias[g]; acc[1][g] = bias[g]; }

#pragma unroll
        for (int ks = 0; ks < 8; ++ks) {
            // contiguous 1KB wave-reads, immediate offsets, 0 conflicts
            bf16x8 af0 = *(const bf16x8*)(buf + ks * 2048 + rb * 64 + c4 * 16);
            bf16x8 af1 = *(const bf16x8*)(buf + ks * 2048 + (16 + rb) * 64 + c4 * 16);
#pragma unroll
            for (int g = 0; g < 4; ++g) {        // swapped operands: D[gatecol][row]
                acc[0][g] = __builtin_amdgcn_mfma_f32_16x16x32_bf16(wfr[g][ks], af0, acc[0][g], 0, 0, 0);
                acc[1][g] = __builtin_amdgcn_mfma_f32_16x16x32_bf16(wfr[g][ks], af1, acc[1][g], 0, 0, 0);
            }
        }

        // stage t+1 into the other buffer (cvtpk waits arrive: issued a full
        // body ago), then start tile t+2's loads into the freed registers.
        if (t + 1 < NT) {
            A_STORE(t + 1);
            if (t + 2 < NT) A_ISSUE(t + 2);
        }

        // c prefetch for next tile
        f32x4 ncv0, ncv1;
        if (t + 1 < NT) {
            ncv0 = *(const f32x4*)(c + (gr0 + TILE + rb) * 128 + gcol4);
            ncv1 = *(const f32x4*)(c + (gr0 + TILE + 16 + rb) * 128 + gcol4);
        }

        // epilogue: in-register combine, float4 stores
#pragma unroll
        for (int mt = 0; mt < 2; ++mt) {
            const f32x4 cv = mt ? cv1 : cv0;
            f32x4 nh, nc;
#pragma unroll
            for (int j = 0; j < 4; ++j) {
                const float g1 = fsig(acc[mt][0][j]);
                const float g2 = fsig(acc[mt][1][j]);
                const float gf = ftanh(acc[mt][2][j]);
                const float g3 = fsig(acc[mt][3][j]);
                nc[j] = cv[j] * g1 + g2 * gf;
                nh[j] = ftanh(nc[j]) * g3;
            }
            const long o = (gr0 + mt * 16 + rb) * 128 + gcol4;
            *(f32x4*)(out_h + o) = nh;
            *(f32x4*)(out_c + o) = nc;
        }

        if (t + 1 < NT) { cv0 = ncv0; cv1 = ncv1; }
    }
}

extern "C" void kernel_launch(void* const* d_in, const int* in_sizes, int n_in,
                              void* d_out, int out_size, void* d_ws, size_t ws_size,
                              hipStream_t stream) {
    (void)in_sizes; (void)n_in; (void)out_size; (void)ws_size;
    const float* x  = (const float*)d_in[0];
    const float* h  = (const float*)d_in[1];
    const float* c  = (const float*)d_in[2];
    const float* W1 = (const float*)d_in[3];
    const float* b1 = (const float*)d_in[4];
    const float* W2 = (const float*)d_in[5];
    const float* b2 = (const float*)d_in[6];
    const float* Wf = (const float*)d_in[7];
    const float* bf = (const float*)d_in[8];
    const float* W3 = (const float*)d_in[9];
    const float* b3 = (const float*)d_in[10];

    wconv_kernel<<<64, 256, 0, stream>>>(W1, W2, Wf, W3, (u32x4*)d_ws);
    lstm_kernel<<<B_TOTAL / NROWB, 512, 0, stream>>>(
        x, h, c, (const bf16x8*)d_ws, b1, b2, bf, b3, (float*)d_out);
}